// Round 7
// baseline (453.726 us; speedup 1.0000x reference)
//
#include <hip/hip_runtime.h>

#define N_NODES 12288
#define N_EDGES 393216
#define IN_FEAT 2000
#define HID 64

typedef __bf16 bf16x8 __attribute__((ext_vector_type(8)));
typedef float f32x16 __attribute__((ext_vector_type(16)));

// ---------------- prep: degree histograms + W1 bf16 hi/lo split (merged) ----------------
__global__ void prep_kernel(const int* __restrict__ src, const int* __restrict__ dst,
                            float* __restrict__ deg_out, float* __restrict__ deg_in,
                            const float* __restrict__ W1, unsigned int* __restrict__ Wpk) {
    int i = blockIdx.x * blockDim.x + threadIdx.x;
    if (i < IN_FEAT * HID) {
        float w = W1[i];
        __bf16 hb = (__bf16)w;
        __bf16 lb = (__bf16)(w - (float)hb);
        Wpk[i] = (unsigned int)__builtin_bit_cast(unsigned short, hb) |
                 ((unsigned int)__builtin_bit_cast(unsigned short, lb) << 16);
    }
    if (i < N_EDGES) {
        atomicAdd(&deg_out[src[i]], 1.0f);
        atomicAdd(&deg_in[dst[i]], 1.0f);
    }
}

// ---------------- CSR offsets: exclusive scan of deg_in (raw counts) ----------------
__global__ __launch_bounds__(1024) void scan_kernel(const float* __restrict__ deg_in,
                                                    int* __restrict__ offs,
                                                    int* __restrict__ cur) {
    __shared__ int sh[1024];
    int t = threadIdx.x;
    int base = t * 12;
    int s = 0;
#pragma unroll
    for (int i = 0; i < 12; ++i) s += (int)deg_in[base + i];
    sh[t] = s;
    __syncthreads();
    for (int off = 1; off < 1024; off <<= 1) {
        int v = (t >= off) ? sh[t - off] : 0;
        __syncthreads();
        sh[t] += v;
        __syncthreads();
    }
    int run = sh[t] - s;
#pragma unroll
    for (int i = 0; i < 12; ++i) {
        int c = (int)deg_in[base + i];
        offs[base + i] = run;
        cur[base + i] = run;
        run += c;
    }
    if (t == 1023) offs[N_NODES] = run;
}

// ---------------- CSR bucket fill: edata[p] = {src[e], bits(ew[e]*out_norm[src])} ----------------
__global__ void fill_kernel(const int* __restrict__ dst, const int* __restrict__ src,
                            const float* __restrict__ ew, const float* __restrict__ deg_out,
                            int* __restrict__ cur, int2* __restrict__ edata) {
    int e = blockIdx.x * blockDim.x + threadIdx.x;
    if (e < N_EDGES) {
        int s = src[e];
        int p = atomicAdd(&cur[dst[e]], 1);
        float wp = ew[e] / sqrtf(fmaxf(deg_out[s], 1.0f));
        edata[p] = make_int2(s, __float_as_int(wp));
    }
}

// ---------------- GEMM1: slab[s] = A @ W1 over K-split s (split-bf16 MFMA, plain stores) ----------------
__global__ __launch_bounds__(256) void gemm1_kernel(const float* __restrict__ A,
                                                    const unsigned int* __restrict__ Wpk,
                                                    float* __restrict__ h,
                                                    float* __restrict__ slabs) {
    __shared__ __align__(16) char As[32768];
    int t = threadIdx.x;
    int w = t >> 6, l = t & 63, lr = l & 31, lh = l >> 5;
    int row0 = blockIdx.x * 64;
    int s = blockIdx.y;
    int ksbase = s * 500;
    float* hout = (s == 0) ? h : slabs + (size_t)(s - 1) * N_NODES * HID;
    int col = (w >> 1) * 32 + lr;
    int lrow = (w & 1) * 32 + lr;
    const char* arow = As + lrow * 512;
    int rx = lr & 7;
    f32x16 acc = {};

    for (int tile = 0; tile < 4; ++tile) {
        int k0 = ksbase + tile * 128;
        int kvalid = (tile < 3) ? 128 : 116;
        __syncthreads();
#pragma unroll
        for (int i = 0; i < 8; ++i) {
            int c = t + i * 256;
            int r = c >> 5, u16 = c & 31;
            float4 v = make_float4(0.f, 0.f, 0.f, 0.f);
            if (u16 * 4 < kvalid)
                v = *(const float4*)&A[(size_t)(row0 + r) * IN_FEAT + k0 + u16 * 4];
            int uu = (u16 >> 1) ^ (r & 7);
            *(float4*)(As + r * 512 + uu * 32 + (u16 & 1) * 16) = v;
        }
        __syncthreads();

#pragma unroll
        for (int kk = 0; kk < 8; ++kk) {
            int uu = (kk * 2 + lh) ^ rx;
            float4 a01 = *(const float4*)(arow + uu * 32);
            float4 a23 = *(const float4*)(arow + uu * 32 + 16);
            float af[8] = {a01.x, a01.y, a01.z, a01.w, a23.x, a23.y, a23.z, a23.w};
            bf16x8 ah, al, wh, wl;
#pragma unroll
            for (int j = 0; j < 8; ++j) {
                float v = af[j];
                __bf16 hb = (__bf16)v;
                ah[j] = hb;
                al[j] = (__bf16)(v - (float)hb);
                int k = k0 + kk * 16 + lh * 8 + j;
                int kc = (k < IN_FEAT) ? k : 0;   // clamp: A is 0 there, keep W finite
                unsigned int wj = Wpk[kc * HID + col];
                wh[j] = __builtin_bit_cast(__bf16, (unsigned short)(wj & 0xffff));
                wl[j] = __builtin_bit_cast(__bf16, (unsigned short)(wj >> 16));
            }
            acc = __builtin_amdgcn_mfma_f32_32x32x16_bf16(ah, wh, acc, 0, 0, 0);
            acc = __builtin_amdgcn_mfma_f32_32x32x16_bf16(ah, wl, acc, 0, 0, 0);
            acc = __builtin_amdgcn_mfma_f32_32x32x16_bf16(al, wh, acc, 0, 0, 0);
        }
    }
#pragma unroll
    for (int r = 0; r < 16; ++r) {
        int orow = row0 + (w & 1) * 32 + (r & 3) + 8 * (r >> 2) + 4 * lh;
        hout[orow * HID + col] = acc[r];
    }
}

// ---------------- hreduce: h += slab1 + slab2 + slab3 (float4) ----------------
__global__ __launch_bounds__(256) void hreduce_kernel(float* __restrict__ h,
                                                      const float* __restrict__ slabs) {
    int g = blockIdx.x * blockDim.x + threadIdx.x;
    float4 a = ((const float4*)h)[g];
    float4 b = ((const float4*)(slabs))[g];
    float4 c = ((const float4*)(slabs + (size_t)N_NODES * HID))[g];
    float4 d = ((const float4*)(slabs + (size_t)2 * N_NODES * HID))[g];
    a.x += b.x + c.x + d.x;
    a.y += b.y + c.y + d.y;
    a.z += b.z + c.z + d.z;
    a.w += b.w + c.w + d.w;
    ((float4*)h)[g] = a;
}

// ---------------- layer1: gather (agg over in-edges) + epilogue + @W2, fused ----------------
__global__ __launch_bounds__(256) void layer1_kernel(const float* __restrict__ h,
                                                     const int2* __restrict__ edata,
                                                     const int* __restrict__ offs,
                                                     const float* __restrict__ deg_in,
                                                     const float* __restrict__ b1,
                                                     const float* __restrict__ W2,
                                                     float* __restrict__ h2) {
    __shared__ float Ws[64 * 64];
    __shared__ float xrow[4][64];
    int t = threadIdx.x;
#pragma unroll
    for (int i = 0; i < 16; ++i) Ws[t + i * 256] = W2[t + i * 256];

    int w = t >> 6;
    int n = blockIdx.x * 4 + w;
    int f = t & 63;
    float acc = 0.f;
    int beg = offs[n], end = offs[n + 1];
    int p = beg;
    for (; p + 4 <= end; p += 4) {
        int2 e0 = edata[p];
        int2 e1 = edata[p + 1];
        int2 e2 = edata[p + 2];
        int2 e3 = edata[p + 3];
        float h0 = h[(size_t)e0.x * HID + f];
        float h1 = h[(size_t)e1.x * HID + f];
        float h2v = h[(size_t)e2.x * HID + f];
        float h3 = h[(size_t)e3.x * HID + f];
        acc = fmaf(h0, __int_as_float(e0.y), acc);
        acc = fmaf(h1, __int_as_float(e1.y), acc);
        acc = fmaf(h2v, __int_as_float(e2.y), acc);
        acc = fmaf(h3, __int_as_float(e3.y), acc);
    }
    for (; p < end; ++p) {
        int2 e = edata[p];
        acc = fmaf(h[(size_t)e.x * HID + f], __int_as_float(e.y), acc);
    }
    float in_norm = 1.0f / sqrtf(fmaxf(deg_in[n], 1.0f));
    float x1 = acc * in_norm + b1[f];

    __syncthreads();                 // Ws staged; all waves ready
    xrow[w][f] = x1;                 // wave-local write->read, lgkmcnt-ordered
    float acc2 = 0.f;
#pragma unroll 16
    for (int k = 0; k < 64; ++k)
        acc2 = fmaf(xrow[w][k], Ws[k * 64 + f], acc2);
    h2[n * HID + f] = acc2;
}

// ---------------- gather layer 2: epilogue (*in_norm + b2) + bf16 hi/lo split ----------------
__global__ __launch_bounds__(256) void gather2_kernel(const float* __restrict__ h,
                                                      const int2* __restrict__ edata,
                                                      const int* __restrict__ offs,
                                                      const float* __restrict__ deg_in,
                                                      const float* __restrict__ b2,
                                                      float* __restrict__ x_out,
                                                      __bf16* __restrict__ xh,
                                                      __bf16* __restrict__ xl) {
    int n = blockIdx.x * 4 + (threadIdx.x >> 6);
    int f = threadIdx.x & 63;
    float acc = 0.f;
    int beg = offs[n], end = offs[n + 1];
    int p = beg;
    for (; p + 4 <= end; p += 4) {
        int2 e0 = edata[p];
        int2 e1 = edata[p + 1];
        int2 e2 = edata[p + 2];
        int2 e3 = edata[p + 3];
        float h0 = h[(size_t)e0.x * HID + f];
        float h1 = h[(size_t)e1.x * HID + f];
        float h2 = h[(size_t)e2.x * HID + f];
        float h3 = h[(size_t)e3.x * HID + f];
        acc = fmaf(h0, __int_as_float(e0.y), acc);
        acc = fmaf(h1, __int_as_float(e1.y), acc);
        acc = fmaf(h2, __int_as_float(e2.y), acc);
        acc = fmaf(h3, __int_as_float(e3.y), acc);
    }
    for (; p < end; ++p) {
        int2 e = edata[p];
        acc = fmaf(h[(size_t)e.x * HID + f], __int_as_float(e.y), acc);
    }
    float in_norm = 1.0f / sqrtf(fmaxf(deg_in[n], 1.0f));
    float x = acc * in_norm + b2[f];
    int g = n * HID + f;
    x_out[g] = x;
    __bf16 hb = (__bf16)x;
    xh[g] = hb;
    xl[g] = (__bf16)(x - (float)hb);
}

// ---------------- decoder: adj = x @ x^T via split-bf16 MFMA (unchanged) ----------------
__global__ __launch_bounds__(256) void adj_kernel(const __bf16* __restrict__ xh,
                                                  const __bf16* __restrict__ xl,
                                                  float* __restrict__ adj) {
    __shared__ __align__(16) char Bh[16384];
    __shared__ __align__(16) char Bl[16384];
    int t = threadIdx.x;
    int w = t >> 6, l = t & 63;
    int lr = l & 31, lh = l >> 5;
    int i0 = blockIdx.x * 128 + w * 32;
    int j0 = blockIdx.y * 128;

    const char* gh = (const char*)(xh + (size_t)j0 * HID);
    const char* gl = (const char*)(xl + (size_t)j0 * HID);
#pragma unroll
    for (int i = 0; i < 4; ++i) {
        int c = t + i * 256;
        int row = c >> 3, cin = c & 7;
        int dst = row * 128 + ((cin ^ (row & 7)) << 4);
        *(float4*)(Bh + dst) = *(const float4*)(gh + c * 16);
        *(float4*)(Bl + dst) = *(const float4*)(gl + c * 16);
    }

    const __bf16* arow_h = xh + (size_t)(i0 + lr) * HID + lh * 8;
    const __bf16* arow_l = xl + (size_t)(i0 + lr) * HID + lh * 8;
    bf16x8 ah[4], al[4];
#pragma unroll
    for (int kc = 0; kc < 4; ++kc) {
        ah[kc] = *(const bf16x8*)(arow_h + kc * 16);
        al[kc] = *(const bf16x8*)(arow_l + kc * 16);
    }
    __syncthreads();

#pragma unroll
    for (int ct = 0; ct < 4; ++ct) {
        int row = ct * 32 + lr;
        int rbase = row * 128, rxx = row & 7;
        bf16x8 bh[4], bl[4];
#pragma unroll
        for (int kc = 0; kc < 4; ++kc) {
            int off = rbase + (((kc * 2 + lh) ^ rxx) << 4);
            bh[kc] = *(const bf16x8*)(Bh + off);
            bl[kc] = *(const bf16x8*)(Bl + off);
        }
        f32x16 acc = {};
        acc = __builtin_amdgcn_mfma_f32_32x32x16_bf16(ah[0], bh[0], acc, 0, 0, 0);
        acc = __builtin_amdgcn_mfma_f32_32x32x16_bf16(ah[1], bh[1], acc, 0, 0, 0);
        acc = __builtin_amdgcn_mfma_f32_32x32x16_bf16(ah[2], bh[2], acc, 0, 0, 0);
        acc = __builtin_amdgcn_mfma_f32_32x32x16_bf16(ah[3], bh[3], acc, 0, 0, 0);
        acc = __builtin_amdgcn_mfma_f32_32x32x16_bf16(ah[0], bl[0], acc, 0, 0, 0);
        acc = __builtin_amdgcn_mfma_f32_32x32x16_bf16(ah[1], bl[1], acc, 0, 0, 0);
        acc = __builtin_amdgcn_mfma_f32_32x32x16_bf16(ah[2], bl[2], acc, 0, 0, 0);
        acc = __builtin_amdgcn_mfma_f32_32x32x16_bf16(ah[3], bl[3], acc, 0, 0, 0);
        acc = __builtin_amdgcn_mfma_f32_32x32x16_bf16(al[0], bh[0], acc, 0, 0, 0);
        acc = __builtin_amdgcn_mfma_f32_32x32x16_bf16(al[1], bh[1], acc, 0, 0, 0);
        acc = __builtin_amdgcn_mfma_f32_32x32x16_bf16(al[2], bh[2], acc, 0, 0, 0);
        acc = __builtin_amdgcn_mfma_f32_32x32x16_bf16(al[3], bh[3], acc, 0, 0, 0);

#pragma unroll
        for (int r = 0; r < 16; ++r) {
            int rrow = (r & 3) + 8 * (r >> 2) + 4 * lh;
            __builtin_nontemporal_store(acc[r],
                &adj[(size_t)(i0 + rrow) * N_NODES + j0 + ct * 32 + lr]);
        }
    }
}

extern "C" void kernel_launch(void* const* d_in, const int* in_sizes, int n_in,
                              void* d_out, int out_size, void* d_ws, size_t ws_size,
                              hipStream_t stream) {
    const float* features = (const float*)d_in[0];
    const float* ew       = (const float*)d_in[1];
    const float* W1       = (const float*)d_in[2];
    const float* b1       = (const float*)d_in[3];
    const float* W2       = (const float*)d_in[4];
    const float* b2       = (const float*)d_in[5];
    const int*   src      = (const int*)d_in[6];
    const int*   dst      = (const int*)d_in[7];

    float* out   = (float*)d_out;
    float* x_out = out + (size_t)N_NODES * N_NODES;

    const size_t NH = (size_t)N_NODES * HID;
    float* ws      = (float*)d_ws;
    float* deg_out = ws;                                  // N (raw counts)
    float* deg_in  = ws + N_NODES;                        // N (raw counts)
    float* h       = ws + 2 * N_NODES;                    // N*HID
    float* slabs   = h + NH;                              // 3 * N*HID (gemm1 splits 1..3)
    int*   offs    = (int*)(slabs + 3 * NH);              // N+1
    int*   cur     = offs + N_NODES + 1;                  // N
    int2*  edata   = (int2*)(cur + N_NODES + 1);          // E int2
    unsigned int* Wpk = (unsigned int*)(edata + N_EDGES); // 2000*64 uint
    float* h2      = (float*)(Wpk + IN_FEAT * HID);       // N*HID (layer-1 output)
    __bf16* xh     = (__bf16*)slabs;                      // overlay (slabs dead after hreduce)
    __bf16* xl     = xh + NH;

    // zero only the degree histograms (96 KB)
    hipMemsetAsync(ws, 0, (size_t)(2 * N_NODES) * sizeof(float), stream);

    prep_kernel<<<N_EDGES / 256, 256, 0, stream>>>(src, dst, deg_out, deg_in, W1, Wpk);
    scan_kernel<<<1, 1024, 0, stream>>>(deg_in, offs, cur);
    fill_kernel<<<N_EDGES / 256, 256, 0, stream>>>(dst, src, ew, deg_out, cur, edata);

    gemm1_kernel<<<dim3(N_NODES / 64, 4), 256, 0, stream>>>(features, Wpk, h, slabs);
    hreduce_kernel<<<(N_NODES * HID / 4) / 256, 256, 0, stream>>>(h, slabs);

    layer1_kernel<<<N_NODES / 4, 256, 0, stream>>>(h, edata, offs, deg_in, b1, W2, h2);

    gather2_kernel<<<N_NODES / 4, 256, 0, stream>>>(h2, edata, offs, deg_in, b2, x_out, xh, xl);

    // PROBE: adj launched twice (identical, deterministic rewrite of the same output).
    // dur_us delta vs R6 (301 us) == adj_kernel's true duration.
    adj_kernel<<<dim3(N_NODES / 128, N_NODES / 128), 256, 0, stream>>>(xh, xl, out);
    adj_kernel<<<dim3(N_NODES / 128, N_NODES / 128), 256, 0, stream>>>(xh, xl, out);
}

// Round 8
// 282.300 us; speedup vs baseline: 1.6072x; 1.6072x over previous
//
#include <hip/hip_runtime.h>

#define N_NODES 12288
#define N_EDGES 393216
#define IN_FEAT 2000
#define HID 64

typedef __bf16 bf16x8 __attribute__((ext_vector_type(8)));
typedef float f32x16 __attribute__((ext_vector_type(16)));

// ---------------- prep: degree histograms + W1 bf16 hi/lo split (merged) ----------------
__global__ void prep_kernel(const int* __restrict__ src, const int* __restrict__ dst,
                            float* __restrict__ deg_out, float* __restrict__ deg_in,
                            const float* __restrict__ W1, unsigned int* __restrict__ Wpk) {
    int i = blockIdx.x * blockDim.x + threadIdx.x;
    if (i < IN_FEAT * HID) {
        float w = W1[i];
        __bf16 hb = (__bf16)w;
        __bf16 lb = (__bf16)(w - (float)hb);
        Wpk[i] = (unsigned int)__builtin_bit_cast(unsigned short, hb) |
                 ((unsigned int)__builtin_bit_cast(unsigned short, lb) << 16);
    }
    if (i < N_EDGES) {
        atomicAdd(&deg_out[src[i]], 1.0f);
        atomicAdd(&deg_in[dst[i]], 1.0f);
    }
}

// ---------------- CSR offsets: exclusive scan of deg_in (raw counts) ----------------
__global__ __launch_bounds__(1024) void scan_kernel(const float* __restrict__ deg_in,
                                                    int* __restrict__ offs,
                                                    int* __restrict__ cur) {
    __shared__ int sh[1024];
    int t = threadIdx.x;
    int base = t * 12;
    int s = 0;
#pragma unroll
    for (int i = 0; i < 12; ++i) s += (int)deg_in[base + i];
    sh[t] = s;
    __syncthreads();
    for (int off = 1; off < 1024; off <<= 1) {
        int v = (t >= off) ? sh[t - off] : 0;
        __syncthreads();
        sh[t] += v;
        __syncthreads();
    }
    int run = sh[t] - s;
#pragma unroll
    for (int i = 0; i < 12; ++i) {
        int c = (int)deg_in[base + i];
        offs[base + i] = run;
        cur[base + i] = run;
        run += c;
    }
    if (t == 1023) offs[N_NODES] = run;
}

// ---------------- CSR bucket fill: edata[p] = {src[e], bits(ew[e]*out_norm[src])} ----------------
__global__ void fill_kernel(const int* __restrict__ dst, const int* __restrict__ src,
                            const float* __restrict__ ew, const float* __restrict__ deg_out,
                            int* __restrict__ cur, int2* __restrict__ edata) {
    int e = blockIdx.x * blockDim.x + threadIdx.x;
    if (e < N_EDGES) {
        int s = src[e];
        int p = atomicAdd(&cur[dst[e]], 1);
        float wp = ew[e] / sqrtf(fmaxf(deg_out[s], 1.0f));
        edata[p] = make_int2(s, __float_as_int(wp));
    }
}

// ---------------- GEMM1: slab[s] = A @ W1 over K-split s (split-bf16 MFMA, plain stores) ----------------
__global__ __launch_bounds__(256) void gemm1_kernel(const float* __restrict__ A,
                                                    const unsigned int* __restrict__ Wpk,
                                                    float* __restrict__ h,
                                                    float* __restrict__ slabs) {
    __shared__ __align__(16) char As[32768];
    int t = threadIdx.x;
    int w = t >> 6, l = t & 63, lr = l & 31, lh = l >> 5;
    int row0 = blockIdx.x * 64;
    int s = blockIdx.y;
    int ksbase = s * 500;
    float* hout = (s == 0) ? h : slabs + (size_t)(s - 1) * N_NODES * HID;
    int col = (w >> 1) * 32 + lr;
    int lrow = (w & 1) * 32 + lr;
    const char* arow = As + lrow * 512;
    int rx = lr & 7;
    f32x16 acc = {};

    for (int tile = 0; tile < 4; ++tile) {
        int k0 = ksbase + tile * 128;
        int kvalid = (tile < 3) ? 128 : 116;
        __syncthreads();
#pragma unroll
        for (int i = 0; i < 8; ++i) {
            int c = t + i * 256;
            int r = c >> 5, u16 = c & 31;
            float4 v = make_float4(0.f, 0.f, 0.f, 0.f);
            if (u16 * 4 < kvalid)
                v = *(const float4*)&A[(size_t)(row0 + r) * IN_FEAT + k0 + u16 * 4];
            int uu = (u16 >> 1) ^ (r & 7);
            *(float4*)(As + r * 512 + uu * 32 + (u16 & 1) * 16) = v;
        }
        __syncthreads();

#pragma unroll
        for (int kk = 0; kk < 8; ++kk) {
            int uu = (kk * 2 + lh) ^ rx;
            float4 a01 = *(const float4*)(arow + uu * 32);
            float4 a23 = *(const float4*)(arow + uu * 32 + 16);
            float af[8] = {a01.x, a01.y, a01.z, a01.w, a23.x, a23.y, a23.z, a23.w};
            bf16x8 ah, al, wh, wl;
#pragma unroll
            for (int j = 0; j < 8; ++j) {
                float v = af[j];
                __bf16 hb = (__bf16)v;
                ah[j] = hb;
                al[j] = (__bf16)(v - (float)hb);
                int k = k0 + kk * 16 + lh * 8 + j;
                int kc = (k < IN_FEAT) ? k : 0;   // clamp: A is 0 there, keep W finite
                unsigned int wj = Wpk[kc * HID + col];
                wh[j] = __builtin_bit_cast(__bf16, (unsigned short)(wj & 0xffff));
                wl[j] = __builtin_bit_cast(__bf16, (unsigned short)(wj >> 16));
            }
            acc = __builtin_amdgcn_mfma_f32_32x32x16_bf16(ah, wh, acc, 0, 0, 0);
            acc = __builtin_amdgcn_mfma_f32_32x32x16_bf16(ah, wl, acc, 0, 0, 0);
            acc = __builtin_amdgcn_mfma_f32_32x32x16_bf16(al, wh, acc, 0, 0, 0);
        }
    }
#pragma unroll
    for (int r = 0; r < 16; ++r) {
        int orow = row0 + (w & 1) * 32 + (r & 3) + 8 * (r >> 2) + 4 * lh;
        hout[orow * HID + col] = acc[r];
    }
}

// ---------------- hreduce: h += slab1 + slab2 + slab3 (float4) ----------------
__global__ __launch_bounds__(256) void hreduce_kernel(float* __restrict__ h,
                                                      const float* __restrict__ slabs) {
    int g = blockIdx.x * blockDim.x + threadIdx.x;
    float4 a = ((const float4*)h)[g];
    float4 b = ((const float4*)(slabs))[g];
    float4 c = ((const float4*)(slabs + (size_t)N_NODES * HID))[g];
    float4 d = ((const float4*)(slabs + (size_t)2 * N_NODES * HID))[g];
    a.x += b.x + c.x + d.x;
    a.y += b.y + c.y + d.y;
    a.z += b.z + c.z + d.z;
    a.w += b.w + c.w + d.w;
    ((float4*)h)[g] = a;
}

// ---------------- layer1: gather (agg over in-edges) + epilogue + @W2, fused ----------------
__global__ __launch_bounds__(256) void layer1_kernel(const float* __restrict__ h,
                                                     const int2* __restrict__ edata,
                                                     const int* __restrict__ offs,
                                                     const float* __restrict__ deg_in,
                                                     const float* __restrict__ b1,
                                                     const float* __restrict__ W2,
                                                     float* __restrict__ h2) {
    __shared__ float Ws[64 * 64];
    __shared__ float xrow[4][64];
    int t = threadIdx.x;
#pragma unroll
    for (int i = 0; i < 16; ++i) Ws[t + i * 256] = W2[t + i * 256];

    int w = t >> 6;
    int n = blockIdx.x * 4 + w;
    int f = t & 63;
    float acc = 0.f;
    int beg = offs[n], end = offs[n + 1];
    int p = beg;
    for (; p + 4 <= end; p += 4) {
        int2 e0 = edata[p];
        int2 e1 = edata[p + 1];
        int2 e2 = edata[p + 2];
        int2 e3 = edata[p + 3];
        float h0 = h[(size_t)e0.x * HID + f];
        float h1 = h[(size_t)e1.x * HID + f];
        float h2v = h[(size_t)e2.x * HID + f];
        float h3 = h[(size_t)e3.x * HID + f];
        acc = fmaf(h0, __int_as_float(e0.y), acc);
        acc = fmaf(h1, __int_as_float(e1.y), acc);
        acc = fmaf(h2v, __int_as_float(e2.y), acc);
        acc = fmaf(h3, __int_as_float(e3.y), acc);
    }
    for (; p < end; ++p) {
        int2 e = edata[p];
        acc = fmaf(h[(size_t)e.x * HID + f], __int_as_float(e.y), acc);
    }
    float in_norm = 1.0f / sqrtf(fmaxf(deg_in[n], 1.0f));
    float x1 = acc * in_norm + b1[f];

    __syncthreads();                 // Ws staged; all waves ready
    xrow[w][f] = x1;                 // wave-local write->read, lgkmcnt-ordered
    float acc2 = 0.f;
#pragma unroll 16
    for (int k = 0; k < 64; ++k)
        acc2 = fmaf(xrow[w][k], Ws[k * 64 + f], acc2);
    h2[n * HID + f] = acc2;
}

// ---------------- gather layer 2: epilogue (*in_norm + b2) + bf16 hi/lo split ----------------
__global__ __launch_bounds__(256) void gather2_kernel(const float* __restrict__ h,
                                                      const int2* __restrict__ edata,
                                                      const int* __restrict__ offs,
                                                      const float* __restrict__ deg_in,
                                                      const float* __restrict__ b2,
                                                      float* __restrict__ x_out,
                                                      __bf16* __restrict__ xh,
                                                      __bf16* __restrict__ xl) {
    int n = blockIdx.x * 4 + (threadIdx.x >> 6);
    int f = threadIdx.x & 63;
    float acc = 0.f;
    int beg = offs[n], end = offs[n + 1];
    int p = beg;
    for (; p + 4 <= end; p += 4) {
        int2 e0 = edata[p];
        int2 e1 = edata[p + 1];
        int2 e2 = edata[p + 2];
        int2 e3 = edata[p + 3];
        float h0 = h[(size_t)e0.x * HID + f];
        float h1 = h[(size_t)e1.x * HID + f];
        float h2 = h[(size_t)e2.x * HID + f];
        float h3 = h[(size_t)e3.x * HID + f];
        acc = fmaf(h0, __int_as_float(e0.y), acc);
        acc = fmaf(h1, __int_as_float(e1.y), acc);
        acc = fmaf(h2, __int_as_float(e2.y), acc);
        acc = fmaf(h3, __int_as_float(e3.y), acc);
    }
    for (; p < end; ++p) {
        int2 e = edata[p];
        acc = fmaf(h[(size_t)e.x * HID + f], __int_as_float(e.y), acc);
    }
    float in_norm = 1.0f / sqrtf(fmaxf(deg_in[n], 1.0f));
    float x = acc * in_norm + b2[f];
    int g = n * HID + f;
    x_out[g] = x;
    __bf16 hb = (__bf16)x;
    xh[g] = hb;
    xl[g] = (__bf16)(x - (float)hb);
}

// ---------------- decoder: adj = x @ x^T via split-bf16 MFMA ----------------
// CHANGES vs R6/R7: (1) plain stores (no nontemporal) so L2 write-combines the
// 604 MB stream; (2) blockIdx.x = j-tile (fastest) so co-resident blocks write
// one contiguous 128-row x 12288-col panel (~6 MB) instead of 512B strips
// scattered across the whole output.
__global__ __launch_bounds__(256) void adj_kernel(const __bf16* __restrict__ xh,
                                                  const __bf16* __restrict__ xl,
                                                  float* __restrict__ adj) {
    __shared__ __align__(16) char Bh[16384];
    __shared__ __align__(16) char Bl[16384];
    int t = threadIdx.x;
    int w = t >> 6, l = t & 63;
    int lr = l & 31, lh = l >> 5;
    int i0 = blockIdx.y * 128 + w * 32;
    int j0 = blockIdx.x * 128;

    const char* gh = (const char*)(xh + (size_t)j0 * HID);
    const char* gl = (const char*)(xl + (size_t)j0 * HID);
#pragma unroll
    for (int i = 0; i < 4; ++i) {
        int c = t + i * 256;
        int row = c >> 3, cin = c & 7;
        int dst = row * 128 + ((cin ^ (row & 7)) << 4);
        *(float4*)(Bh + dst) = *(const float4*)(gh + c * 16);
        *(float4*)(Bl + dst) = *(const float4*)(gl + c * 16);
    }

    const __bf16* arow_h = xh + (size_t)(i0 + lr) * HID + lh * 8;
    const __bf16* arow_l = xl + (size_t)(i0 + lr) * HID + lh * 8;
    bf16x8 ah[4], al[4];
#pragma unroll
    for (int kc = 0; kc < 4; ++kc) {
        ah[kc] = *(const bf16x8*)(arow_h + kc * 16);
        al[kc] = *(const bf16x8*)(arow_l + kc * 16);
    }
    __syncthreads();

#pragma unroll
    for (int ct = 0; ct < 4; ++ct) {
        int row = ct * 32 + lr;
        int rbase = row * 128, rxx = row & 7;
        bf16x8 bh[4], bl[4];
#pragma unroll
        for (int kc = 0; kc < 4; ++kc) {
            int off = rbase + (((kc * 2 + lh) ^ rxx) << 4);
            bh[kc] = *(const bf16x8*)(Bh + off);
            bl[kc] = *(const bf16x8*)(Bl + off);
        }
        f32x16 acc = {};
        acc = __builtin_amdgcn_mfma_f32_32x32x16_bf16(ah[0], bh[0], acc, 0, 0, 0);
        acc = __builtin_amdgcn_mfma_f32_32x32x16_bf16(ah[1], bh[1], acc, 0, 0, 0);
        acc = __builtin_amdgcn_mfma_f32_32x32x16_bf16(ah[2], bh[2], acc, 0, 0, 0);
        acc = __builtin_amdgcn_mfma_f32_32x32x16_bf16(ah[3], bh[3], acc, 0, 0, 0);
        acc = __builtin_amdgcn_mfma_f32_32x32x16_bf16(ah[0], bl[0], acc, 0, 0, 0);
        acc = __builtin_amdgcn_mfma_f32_32x32x16_bf16(ah[1], bl[1], acc, 0, 0, 0);
        acc = __builtin_amdgcn_mfma_f32_32x32x16_bf16(ah[2], bl[2], acc, 0, 0, 0);
        acc = __builtin_amdgcn_mfma_f32_32x32x16_bf16(ah[3], bl[3], acc, 0, 0, 0);
        acc = __builtin_amdgcn_mfma_f32_32x32x16_bf16(al[0], bh[0], acc, 0, 0, 0);
        acc = __builtin_amdgcn_mfma_f32_32x32x16_bf16(al[1], bh[1], acc, 0, 0, 0);
        acc = __builtin_amdgcn_mfma_f32_32x32x16_bf16(al[2], bh[2], acc, 0, 0, 0);
        acc = __builtin_amdgcn_mfma_f32_32x32x16_bf16(al[3], bh[3], acc, 0, 0, 0);

#pragma unroll
        for (int r = 0; r < 16; ++r) {
            int rrow = (r & 3) + 8 * (r >> 2) + 4 * lh;
            adj[(size_t)(i0 + rrow) * N_NODES + j0 + ct * 32 + lr] = acc[r];
        }
    }
}

extern "C" void kernel_launch(void* const* d_in, const int* in_sizes, int n_in,
                              void* d_out, int out_size, void* d_ws, size_t ws_size,
                              hipStream_t stream) {
    const float* features = (const float*)d_in[0];
    const float* ew       = (const float*)d_in[1];
    const float* W1       = (const float*)d_in[2];
    const float* b1       = (const float*)d_in[3];
    const float* W2       = (const float*)d_in[4];
    const float* b2       = (const float*)d_in[5];
    const int*   src      = (const int*)d_in[6];
    const int*   dst      = (const int*)d_in[7];

    float* out   = (float*)d_out;
    float* x_out = out + (size_t)N_NODES * N_NODES;

    const size_t NH = (size_t)N_NODES * HID;
    float* ws      = (float*)d_ws;
    float* deg_out = ws;                                  // N (raw counts)
    float* deg_in  = ws + N_NODES;                        // N (raw counts)
    float* h       = ws + 2 * N_NODES;                    // N*HID
    float* slabs   = h + NH;                              // 3 * N*HID (gemm1 splits 1..3)
    int*   offs    = (int*)(slabs + 3 * NH);              // N+1
    int*   cur     = offs + N_NODES + 1;                  // N
    int2*  edata   = (int2*)(cur + N_NODES + 1);          // E int2
    unsigned int* Wpk = (unsigned int*)(edata + N_EDGES); // 2000*64 uint
    float* h2      = (float*)(Wpk + IN_FEAT * HID);       // N*HID (layer-1 output)
    __bf16* xh     = (__bf16*)slabs;                      // overlay (slabs dead after hreduce)
    __bf16* xl     = xh + NH;

    // zero only the degree histograms (96 KB)
    hipMemsetAsync(ws, 0, (size_t)(2 * N_NODES) * sizeof(float), stream);

    prep_kernel<<<N_EDGES / 256, 256, 0, stream>>>(src, dst, deg_out, deg_in, W1, Wpk);
    scan_kernel<<<1, 1024, 0, stream>>>(deg_in, offs, cur);
    fill_kernel<<<N_EDGES / 256, 256, 0, stream>>>(dst, src, ew, deg_out, cur, edata);

    gemm1_kernel<<<dim3(N_NODES / 64, 4), 256, 0, stream>>>(features, Wpk, h, slabs);
    hreduce_kernel<<<(N_NODES * HID / 4) / 256, 256, 0, stream>>>(h, slabs);

    layer1_kernel<<<N_NODES / 4, 256, 0, stream>>>(h, edata, offs, deg_in, b1, W2, h2);

    gather2_kernel<<<N_NODES / 4, 256, 0, stream>>>(h2, edata, offs, deg_in, b2, x_out, xh, xl);

    adj_kernel<<<dim3(N_NODES / 128, N_NODES / 128), 256, 0, stream>>>(xh, xl, out);
}